// Round 11
// baseline (67.957 us; speedup 1.0000x reference)
//
#include <hip/hip_runtime.h>
#include <stdint.h>

#define NCLS 80
#define BGI 80
#define BB 16
#define NGT 32
#define MM 33600
#define EPSF 1e-9f
#define CAP 1024
#define ZPB 21000  // float4 per zero block: 512*21000 == 10752000 == B*M*80/4

// IoU exactly mirroring reference pairwise_iou op order; no FMA contraction.
__device__ __forceinline__ float iou_f(const float4 b1, const float4 b2) {
#pragma clang fp contract(off)
  float ltx = fmaxf(b1.x, b2.x);
  float lty = fmaxf(b1.y, b2.y);
  float rbx = fminf(b1.z, b2.z);
  float rby = fminf(b1.w, b2.w);
  float iw = fmaxf(rbx - ltx, 0.0f);
  float ih = fmaxf(rby - lty, 0.0f);
  float inter = iw * ih;
  float a1 = (b1.z - b1.x) * (b1.w - b1.y);
  float a2 = (b2.z - b2.x) * (b2.w - b2.y);
  return inter / (a1 + a2 - inter + EPSF);
}

// P0: precompute anchor centers (same op order as reference anchor_points)
// and zero the packed (cnt|g-sum) scatter array. 2100*256 == 537600 exact.
__global__ __launch_bounds__(256) void k_prep(
    const float4* __restrict__ anchors, float2* __restrict__ centers,
    unsigned int* __restrict__ pk) {
#pragma clang fp contract(off)
  const int i = blockIdx.x * 256 + threadIdx.x;
  if (i < MM) {
    const float4 ab = anchors[i];
    centers[i] = make_float2((ab.x + ab.z) * 0.5f, (ab.y + ab.w) * 0.5f);
  }
  pk[i] = 0u;
}

// K1 parity-hybrid: 1024 uniform 1024-thread blocks.
//   even blockIdx -> top-k for pair (blockIdx>>1)  [R8-proven body, untouched]
//   odd  blockIdx -> zero-writer for score slice (blockIdx>>1)
// Uniform size (16 waves, VGPR<=64, LDS 8.5KB) -> 2 blocks/CU; breadth-first
// dispatch of interleaved parities co-locates ~1 scan block + ~1 store block
// per CU, so the 172MB zero drain runs on separate waves from the
// latency-bound scans (no shared vmcnt queue, no barrier-drain coupling).
//
// Top-k = bound-then-rank:
//  pass1: per-thread min of SQUARED dist -> 16 wave minima; wave 0 computes
//         T = sqrt(9th smallest) (monotone sqrt commutes with min/rank).
//         Valid upper bound on true 9th distance: <9 elements can be < K9.
//  pass2: dist = sqrt(d2) (reference rounding); collect keys
//         (distbits<<32|idx) with dist<=T into LDS.
//  rank:  rank = #smaller keys; keys unique via idx low bits -> exact top-9
//         with lax.top_k tie semantics (equal dist -> smaller index).
__global__ __launch_bounds__(1024) void k_topk(
    const float4* __restrict__ anchors, const float2* __restrict__ centers,
    const float4* __restrict__ gtb, const float* __restrict__ maskgt,
    unsigned int* __restrict__ pk, float4* __restrict__ zscores) {
#pragma clang fp contract(off)
  const int tid = threadIdx.x;

  if (blockIdx.x & 1) {  // ---- odd: zero-writer block
    const int zb = (int)blockIdx.x >> 1;  // 0..511
    float4* z = zscores + (size_t)zb * ZPB;
    const float4 zero4 = make_float4(0.f, 0.f, 0.f, 0.f);
#pragma unroll
    for (int it = 0; it < 21; ++it) {  // 20*1024 + 520 = 21000 (predicated)
      const int idx = it * 1024 + tid;
      if (idx < ZPB) z[idx] = zero4;
    }
    return;
  }

  const int pair = (int)blockIdx.x >> 1;  // b*32+g
  if (maskgt[pair] == 0.0f) return;       // masked gt contributes nothing
  const int b = pair >> 5;
  const int g = pair & 31;
  const int lane = tid & 63;
  const int wid = tid >> 6;
  const float4 gb = gtb[pair];
  const float gcx = (gb.x + gb.z) * 0.5f;
  const float gcy = (gb.y + gb.w) * 0.5f;

  __shared__ unsigned long long buf[CAP];
  __shared__ unsigned long long winners[27];
  __shared__ float s_wmin[16];
  __shared__ float s_T;
  __shared__ unsigned int s_cnt;

  const int LSTART[3] = {0, 25600, 32000};
  const int LLEN[3]   = {25600, 6400, 1600};

#pragma unroll
  for (int lev = 0; lev < 3; ++lev) {
    const int start = LSTART[lev];
    const int len = LLEN[lev];

    // pass 1: branch-free per-thread min of squared distance (no sqrt)
    float mymin = 3.4e38f;
    for (int j = tid; j < len; j += 1024) {
      const float2 ac = centers[start + j];
      const float dx = gcx - ac.x;
      const float dy = gcy - ac.y;
      mymin = fminf(mymin, dx * dx + dy * dy);
    }
#pragma unroll
    for (int s = 32; s >= 1; s >>= 1)
      mymin = fminf(mymin, __shfl_xor(mymin, s, 64));
    if (lane == 0) s_wmin[wid] = mymin;
    if (tid == 0) s_cnt = 0u;
    __syncthreads();

    // T = sqrt(9th smallest of the 16 squared wave minima), wave 0 only
    if (wid == 0 && lane < 16) {
      const float v = s_wmin[lane];
      int r = 0;
#pragma unroll
      for (int q = 0; q < 16; ++q) {
        const float o = s_wmin[q];
        r += (o < v) || (o == v && q < lane);
      }
      if (r == 8) s_T = sqrtf(v);  // unique rank -> exactly one lane
    }
    __syncthreads();
    const float T = s_T;

    // pass 2: collect candidates with sqrt'd dist (reference rounding)
    for (int j = tid; j < len; j += 1024) {
      const float2 ac = centers[start + j];
      const float dx = gcx - ac.x;
      const float dy = gcy - ac.y;
      const float dist = sqrtf(dx * dx + dy * dy);
      if (dist <= T) {
        const unsigned int p = atomicAdd(&s_cnt, 1u);
        if (p < CAP)
          buf[p] = ((unsigned long long)__float_as_uint(dist) << 32) |
                   (unsigned long long)(unsigned int)(start + j);
      }
    }
    __syncthreads();

    const int m = (int)min(s_cnt, (unsigned int)CAP);
    // rank-select: exactly 9 winners (keys unique -> ranks unique)
    for (int i = tid; i < m; i += 1024) {
      const unsigned long long k = buf[i];
      int r = 0;
      for (int q = 0; q < m; ++q) r += (buf[q] < k);
      if (r < 9) winners[lev * 9 + r] = k;
    }
    __syncthreads();
  }

  if (wid != 0) return;  // wave 0 finishes; no more barriers

  unsigned int mycand = 0;
  if (lane < 27) mycand = (unsigned int)(winners[lane] & 0xffffffffu);

  // candidate IoUs + inside-gt test (lanes 0..26)
  float ov = 0.0f;
  bool inside = false;
  if (lane < 27) {
    const float4 ab = anchors[mycand];
    ov = iou_f(gb, ab);
    const float2 ac = centers[mycand];
    const float m1 = fminf(fminf(ac.x - gb.x, ac.y - gb.y),
                           fminf(gb.z - ac.x, gb.w - ac.y));
    inside = m1 > EPSF;
  }
  // thr = mean + std(ddof=1) over the 27 gathered IoUs
  float s = (lane < 27) ? ov : 0.0f;
#pragma unroll
  for (int sft = 32; sft >= 1; sft >>= 1) s += __shfl_xor(s, sft, 64);
  const float mean = s / 27.0f;
  float dev = (lane < 27) ? (ov - mean) : 0.0f;
  float s2 = dev * dev;
#pragma unroll
  for (int sft = 32; sft >= 1; sft >>= 1) s2 += __shfl_xor(s2, sft, 64);
  const float thr = mean + sqrtf(s2 / 26.0f);

  if (lane < 27 && inside && ov > thr) {
    // packed: cnt in bits[31:20], sum of g in bits[19:0].
    // <=32 adds: cnt<=32, g-sum<=992 -> no field overflow; cnt==1 -> low=g.
    atomicAdd(&pk[b * MM + (int)mycand], (1u << 20) | (unsigned int)g);
  }
}

// B1 sparse: per (b,a) resolve assignment; write labels/bbox/fg and — since
// the score tensor is pre-zeroed by k_topk's zero blocks — ONE scalar score
// per fg anchor.
__global__ __launch_bounds__(256) void k_out(
    const float4* __restrict__ anchors, const float4* __restrict__ gtb,
    const int* __restrict__ glabels, const float4* __restrict__ predb,
    const unsigned int* __restrict__ pk,
    float* __restrict__ out_labels, float4* __restrict__ out_bbox,
    float* __restrict__ out_fg, float* __restrict__ out_scores) {
  const int a = blockIdx.x * 256 + threadIdx.x;
  if (a >= MM) return;
  const int b = blockIdx.y;
  const int i = b * MM + a;
  const unsigned int p = pk[i];
  const unsigned int c = p >> 20;
  int g = 0;
  const bool fg = (c != 0u);
  if (c == 1u) {
    g = (int)(p & 0xFFFFFu);
  } else if (c > 1u) {
    // reference: column replaced by one_hot(argmax_g overlaps) — includes
    // masked gts; first-max tie-break like jnp.argmax.
    const float4 ab = anchors[a];
    float best = -1.0f;
    for (int gg = 0; gg < NGT; ++gg) {
      const float ovv = iou_f(gtb[b * NGT + gg], ab);
      if (ovv > best) { best = ovv; g = gg; }
    }
  }
  const int lbl = fg ? glabels[b * NGT + g] : BGI;
  out_labels[i] = (float)lbl;
  out_bbox[i] = gtb[b * NGT + g];  // !fg -> g==0 (argmax of zeros)
  out_fg[i] = fg ? 1.0f : 0.0f;
  if (fg) {
    const float io = iou_f(gtb[b * NGT + g], predb[i]);
    out_scores[(size_t)i * NCLS + lbl] = io;  // rest of row stays zero
  }
}

extern "C" void kernel_launch(void* const* d_in, const int* in_sizes, int n_in,
                              void* d_out, int out_size, void* d_ws, size_t ws_size,
                              hipStream_t stream) {
  // Identify inputs by size (robust to how the n_level tuple is passed).
  const float* anchors = nullptr;
  const float* gtb = nullptr;
  const int* glab = nullptr;
  const float* maskgt = nullptr;
  const float* predb = nullptr;
  int seen512 = 0;
  for (int i = 0; i < n_in; ++i) {
    const int sz = in_sizes[i];
    if (sz == 134400 && !anchors) anchors = (const float*)d_in[i];
    else if (sz == 2048 && !gtb) gtb = (const float*)d_in[i];
    else if (sz == 512) {
      if (seen512++ == 0) glab = (const int*)d_in[i];
      else maskgt = (const float*)d_in[i];
    } else if (sz == 2150400 && !predb) predb = (const float*)d_in[i];
  }
  if (!anchors || !gtb || !glab || !maskgt || !predb) return;  // defensive

  float* out = (float*)d_out;
  float* out_labels = out;                          // [B*M]
  float4* out_bbox = (float4*)(out + 537600);       // [B*M][4]
  float* out_scores = out + 2688000;                // [B*M][80]
  float* out_fg = out + 45696000;                   // [B*M]

  unsigned int* pk = (unsigned int*)d_ws;           // [B*M] packed cnt|gsum
  float2* centers = (float2*)(pk + 537600);         // [M], 8B-aligned

  k_prep<<<dim3(2100), dim3(256), 0, stream>>>(
      (const float4*)anchors, centers, pk);

  k_topk<<<dim3(1024), dim3(1024), 0, stream>>>(
      (const float4*)anchors, centers, (const float4*)gtb, maskgt, pk,
      (float4*)out_scores);

  k_out<<<dim3(132, BB), dim3(256), 0, stream>>>(
      (const float4*)anchors, (const float4*)gtb, glab, (const float4*)predb,
      pk, out_labels, out_bbox, out_fg, out_scores);
}

// Round 12
// 54.110 us; speedup vs baseline: 1.2559x; 1.2559x over previous
//
#include <hip/hip_runtime.h>
#include <stdint.h>

#define NCLS 80
#define BGI 80
#define BB 16
#define NGT 32
#define MM 33600
#define EPSF 1e-9f
#define CAP 1024
#define ZPB 21000  // float4 per zero block: 512*21000 == 10752000 == B*M*80/4

// IoU exactly mirroring reference pairwise_iou op order; no FMA contraction.
__device__ __forceinline__ float iou_f(const float4 b1, const float4 b2) {
#pragma clang fp contract(off)
  float ltx = fmaxf(b1.x, b2.x);
  float lty = fmaxf(b1.y, b2.y);
  float rbx = fminf(b1.z, b2.z);
  float rby = fminf(b1.w, b2.w);
  float iw = fmaxf(rbx - ltx, 0.0f);
  float ih = fmaxf(rby - lty, 0.0f);
  float inter = iw * ih;
  float a1 = (b1.z - b1.x) * (b1.w - b1.y);
  float a2 = (b2.z - b2.x) * (b2.w - b2.y);
  return inter / (a1 + a2 - inter + EPSF);
}

// P0: precompute anchor centers (same op order as reference anchor_points)
// and zero the packed (cnt|g-sum) scatter array. 2100*256 == 537600 exact.
__global__ __launch_bounds__(256) void k_prep(
    const float4* __restrict__ anchors, float2* __restrict__ centers,
    unsigned int* __restrict__ pk) {
#pragma clang fp contract(off)
  const int i = blockIdx.x * 256 + threadIdx.x;
  if (i < MM) {
    const float4 ab = anchors[i];
    centers[i] = make_float2((ab.x + ab.z) * 0.5f, (ab.y + ab.w) * 0.5f);
  }
  pk[i] = 0u;
}

// K1 hybrid: 1024 uniform 1024-thread blocks; type = (blockIdx>>8)&1.
// CU slot assignment is blockIdx mod 256 (or mod-8-XCD equivalent), so blocks
// j and j+256 share a CU and have DIFFERENT types -> every CU co-hosts one
// scan block + one zero-writer block from t=0. The 172MB zero drain runs on
// separate waves (own vmcnt queue, no barrier coupling) under the
// latency-bound scans.
//
// Top-k = bound-then-rank (R8-proven semantics), float4 scan (2 centers/iter):
//  pass1: per-thread min of SQUARED dist -> 16 wave minima; wave 0 computes
//         T = sqrt(9th smallest). Valid for ANY 16-way partition: the 9
//         smallest partition-minima are 9 distinct elements <= T => K9 <= T.
//         Monotone sqrt commutes with min/rank.
//  pass2: per-element dist = sqrt(d2) (reference rounding); collect keys
//         (distbits<<32|idx) with dist<=T into LDS.
//  rank:  rank = #smaller keys; keys unique via idx low bits -> exact top-9
//         with lax.top_k tie semantics (equal dist -> smaller index).
__global__ __launch_bounds__(1024) void k_topk(
    const float4* __restrict__ anchors, const float2* __restrict__ centers,
    const float4* __restrict__ gtb, const float* __restrict__ maskgt,
    unsigned int* __restrict__ pk, float4* __restrict__ zscores) {
#pragma clang fp contract(off)
  const int tid = threadIdx.x;
  const int bid = (int)blockIdx.x;

  if ((bid >> 8) & 1) {  // ---- zero-writer block
    const int zb = (bid & 255) | ((bid >> 9) << 8);  // 0..511
    float4* z = zscores + (size_t)zb * ZPB;
    const float4 zero4 = make_float4(0.f, 0.f, 0.f, 0.f);
#pragma unroll
    for (int it = 0; it < 21; ++it) {  // 21*1024 covers 21000 (predicated)
      const int idx = it * 1024 + tid;
      if (idx < ZPB) z[idx] = zero4;
    }
    return;
  }

  const int pair = (bid & 255) | ((bid >> 9) << 8);  // 0..511 == b*32+g
  if (maskgt[pair] == 0.0f) return;       // masked gt contributes nothing
  const int b = pair >> 5;
  const int g = pair & 31;
  const int lane = tid & 63;
  const int wid = tid >> 6;
  const float4 gb = gtb[pair];
  const float gcx = (gb.x + gb.z) * 0.5f;
  const float gcy = (gb.y + gb.w) * 0.5f;

  __shared__ unsigned long long buf[CAP];
  __shared__ unsigned long long winners[27];
  __shared__ float s_wmin[16];
  __shared__ float s_T;
  __shared__ unsigned int s_cnt;

  const int LSTART[3] = {0, 25600, 32000};
  const int LLEN[3]   = {25600, 6400, 1600};

#pragma unroll
  for (int lev = 0; lev < 3; ++lev) {
    const int start = LSTART[lev];
    const int len2 = LLEN[lev] >> 1;  // pairs of centers
    const float4* c4 = (const float4*)(centers + start);  // 16B-aligned

    // pass 1: branch-free per-thread min of squared distance, 2 centers/load
    float mymin = 3.4e38f;
    for (int p = tid; p < len2; p += 1024) {
      const float4 two = c4[p];
      const float dx0 = gcx - two.x, dy0 = gcy - two.y;
      const float dx1 = gcx - two.z, dy1 = gcy - two.w;
      mymin = fminf(mymin,
                    fminf(dx0 * dx0 + dy0 * dy0, dx1 * dx1 + dy1 * dy1));
    }
#pragma unroll
    for (int s = 32; s >= 1; s >>= 1)
      mymin = fminf(mymin, __shfl_xor(mymin, s, 64));
    if (lane == 0) s_wmin[wid] = mymin;
    if (tid == 0) s_cnt = 0u;
    __syncthreads();

    // T = sqrt(9th smallest of the 16 squared wave minima), wave 0 only
    if (wid == 0 && lane < 16) {
      const float v = s_wmin[lane];
      int r = 0;
#pragma unroll
      for (int q = 0; q < 16; ++q) {
        const float o = s_wmin[q];
        r += (o < v) || (o == v && q < lane);
      }
      if (r == 8) s_T = sqrtf(v);  // unique rank -> exactly one lane
    }
    __syncthreads();
    const float T = s_T;

    // pass 2: collect candidates with per-element sqrt'd dist
    for (int p = tid; p < len2; p += 1024) {
      const float4 two = c4[p];
      const float dx0 = gcx - two.x, dy0 = gcy - two.y;
      const float dx1 = gcx - two.z, dy1 = gcy - two.w;
      const float dist0 = sqrtf(dx0 * dx0 + dy0 * dy0);
      const float dist1 = sqrtf(dx1 * dx1 + dy1 * dy1);
      if (dist0 <= T) {
        const unsigned int q = atomicAdd(&s_cnt, 1u);
        if (q < CAP)
          buf[q] = ((unsigned long long)__float_as_uint(dist0) << 32) |
                   (unsigned long long)(unsigned int)(start + 2 * p);
      }
      if (dist1 <= T) {
        const unsigned int q = atomicAdd(&s_cnt, 1u);
        if (q < CAP)
          buf[q] = ((unsigned long long)__float_as_uint(dist1) << 32) |
                   (unsigned long long)(unsigned int)(start + 2 * p + 1);
      }
    }
    __syncthreads();

    const int m = (int)min(s_cnt, (unsigned int)CAP);
    // rank-select: exactly 9 winners (keys unique -> ranks unique)
    for (int i = tid; i < m; i += 1024) {
      const unsigned long long k = buf[i];
      int r = 0;
      for (int q = 0; q < m; ++q) r += (buf[q] < k);
      if (r < 9) winners[lev * 9 + r] = k;
    }
    __syncthreads();
  }

  if (wid != 0) return;  // wave 0 finishes; no more barriers

  unsigned int mycand = 0;
  if (lane < 27) mycand = (unsigned int)(winners[lane] & 0xffffffffu);

  // candidate IoUs + inside-gt test (lanes 0..26)
  float ov = 0.0f;
  bool inside = false;
  if (lane < 27) {
    const float4 ab = anchors[mycand];
    ov = iou_f(gb, ab);
    const float2 ac = centers[mycand];
    const float m1 = fminf(fminf(ac.x - gb.x, ac.y - gb.y),
                           fminf(gb.z - ac.x, gb.w - ac.y));
    inside = m1 > EPSF;
  }
  // thr = mean + std(ddof=1) over the 27 gathered IoUs
  float s = (lane < 27) ? ov : 0.0f;
#pragma unroll
  for (int sft = 32; sft >= 1; sft >>= 1) s += __shfl_xor(s, sft, 64);
  const float mean = s / 27.0f;
  float dev = (lane < 27) ? (ov - mean) : 0.0f;
  float s2 = dev * dev;
#pragma unroll
  for (int sft = 32; sft >= 1; sft >>= 1) s2 += __shfl_xor(s2, sft, 64);
  const float thr = mean + sqrtf(s2 / 26.0f);

  if (lane < 27 && inside && ov > thr) {
    // packed: cnt in bits[31:20], sum of g in bits[19:0].
    // <=32 adds: cnt<=32, g-sum<=992 -> no field overflow; cnt==1 -> low=g.
    atomicAdd(&pk[b * MM + (int)mycand], (1u << 20) | (unsigned int)g);
  }
}

// B1 sparse: per (b,a) resolve assignment; write labels/bbox/fg and — since
// the score tensor is pre-zeroed by k_topk's zero blocks — ONE scalar score
// per fg anchor.
__global__ __launch_bounds__(256) void k_out(
    const float4* __restrict__ anchors, const float4* __restrict__ gtb,
    const int* __restrict__ glabels, const float4* __restrict__ predb,
    const unsigned int* __restrict__ pk,
    float* __restrict__ out_labels, float4* __restrict__ out_bbox,
    float* __restrict__ out_fg, float* __restrict__ out_scores) {
  const int a = blockIdx.x * 256 + threadIdx.x;
  if (a >= MM) return;
  const int b = blockIdx.y;
  const int i = b * MM + a;
  const unsigned int p = pk[i];
  const unsigned int c = p >> 20;
  int g = 0;
  const bool fg = (c != 0u);
  if (c == 1u) {
    g = (int)(p & 0xFFFFFu);
  } else if (c > 1u) {
    // reference: column replaced by one_hot(argmax_g overlaps) — includes
    // masked gts; first-max tie-break like jnp.argmax.
    const float4 ab = anchors[a];
    float best = -1.0f;
    for (int gg = 0; gg < NGT; ++gg) {
      const float ovv = iou_f(gtb[b * NGT + gg], ab);
      if (ovv > best) { best = ovv; g = gg; }
    }
  }
  const int lbl = fg ? glabels[b * NGT + g] : BGI;
  out_labels[i] = (float)lbl;
  out_bbox[i] = gtb[b * NGT + g];  // !fg -> g==0 (argmax of zeros)
  out_fg[i] = fg ? 1.0f : 0.0f;
  if (fg) {
    const float io = iou_f(gtb[b * NGT + g], predb[i]);
    out_scores[(size_t)i * NCLS + lbl] = io;  // rest of row stays zero
  }
}

extern "C" void kernel_launch(void* const* d_in, const int* in_sizes, int n_in,
                              void* d_out, int out_size, void* d_ws, size_t ws_size,
                              hipStream_t stream) {
  // Identify inputs by size (robust to how the n_level tuple is passed).
  const float* anchors = nullptr;
  const float* gtb = nullptr;
  const int* glab = nullptr;
  const float* maskgt = nullptr;
  const float* predb = nullptr;
  int seen512 = 0;
  for (int i = 0; i < n_in; ++i) {
    const int sz = in_sizes[i];
    if (sz == 134400 && !anchors) anchors = (const float*)d_in[i];
    else if (sz == 2048 && !gtb) gtb = (const float*)d_in[i];
    else if (sz == 512) {
      if (seen512++ == 0) glab = (const int*)d_in[i];
      else maskgt = (const float*)d_in[i];
    } else if (sz == 2150400 && !predb) predb = (const float*)d_in[i];
  }
  if (!anchors || !gtb || !glab || !maskgt || !predb) return;  // defensive

  float* out = (float*)d_out;
  float* out_labels = out;                          // [B*M]
  float4* out_bbox = (float4*)(out + 537600);       // [B*M][4]
  float* out_scores = out + 2688000;                // [B*M][80]
  float* out_fg = out + 45696000;                   // [B*M]

  unsigned int* pk = (unsigned int*)d_ws;           // [B*M] packed cnt|gsum
  float2* centers = (float2*)(pk + 537600);         // [M], 16B-aligned

  k_prep<<<dim3(2100), dim3(256), 0, stream>>>(
      (const float4*)anchors, centers, pk);

  k_topk<<<dim3(1024), dim3(1024), 0, stream>>>(
      (const float4*)anchors, centers, (const float4*)gtb, maskgt, pk,
      (float4*)out_scores);

  k_out<<<dim3(132, BB), dim3(256), 0, stream>>>(
      (const float4*)anchors, (const float4*)gtb, glab, (const float4*)predb,
      pk, out_labels, out_bbox, out_fg, out_scores);
}